// Round 20
// baseline (199.289 us; speedup 1.0000x reference)
//
#include <hip/hip_runtime.h>

// SparseResidualBlock: bn1->silu->sparseconv1(+t_emb)->bn2->silu->sparseconv2 + (x@res_W+res_b)
// N=50000, FIN=64, FOUT=128, K=27, B=4, TEMB=256. Output f32 [N,128].
//
// R20 = R19 (8-wave blocks, rolled dbuf pipeline, depth-2 B-prefetch) +
// fout-split x2: block (vb,h) = 128 vox x 64 fout -> grid 782 (3.05 blk/CU
// vs R19's 1.53 - occupancy was grid-limited at 29%). acc halves to 16 VGPR.
// conv2: 27 periods x 16KB (tap,half) chunk x 16 MFMAs. conv1: 27 x 8KB x 8.
// Gather FETCH doubles (L2/LLC-absorbed; HBM at 16%). R16's fout-split
// failed only because 2-wave blocks couldn't raise occupancy - 8-wave can.

#define EPS 1e-5f

typedef __attribute__((ext_vector_type(8))) short s16x8;
typedef __attribute__((ext_vector_type(4))) float f32x4;
typedef __attribute__((ext_vector_type(4))) unsigned short u16x4;

static __device__ __forceinline__ unsigned short f2bf(float f) {
    union { float f; unsigned u; } v; v.f = f;
    unsigned r = v.u + 0x7fffu + ((v.u >> 16) & 1u);   // RTNE
    return (unsigned short)(r >> 16);
}
static __device__ __forceinline__ float silu_d(float x) {
    return x / (1.f + __expf(-x));
}
static __device__ __forceinline__ void gload_lds16(const void* gsrc, void* ldst) {
    __builtin_amdgcn_global_load_lds(
        (const __attribute__((address_space(1))) unsigned int*)gsrc,
        (__attribute__((address_space(3))) unsigned int*)ldst, 16, 0, 0);
}
// mask stored as 1-byte bool (shift 0) or int32 (shift 2)? Probe a byte at a
// non-multiple-of-4 index inside the all-true center row (k=13).
static __device__ __forceinline__ int mask_shift(const unsigned char* mask, int NV) {
    size_t base = (size_t)13 * (size_t)NV;
    int v = ((base & 3) == 3) ? 2 : 1;
    return (mask[base + v] == 1) ? 0 : 2;
}

// ---------------- prep: t_emb + bn2 scale/shift ----------------
__global__ void k_prep_small(const float* __restrict__ t, const float* __restrict__ tW,
                             const float* __restrict__ tb,
                             const float* __restrict__ g2, const float* __restrict__ b2,
                             const float* __restrict__ m2, const float* __restrict__ v2,
                             float* __restrict__ temb, float* __restrict__ sc,
                             float* __restrict__ sh, int B) {
    int tid = threadIdx.x;
    if (tid < B * 128) {
        int b = tid >> 7, o = tid & 127;
        float s = 0.f;
        for (int e = 0; e < 256; ++e) {
            float tv = t[b * 256 + e];
            s += silu_d(tv) * tW[e * 128 + o];
        }
        temb[tid] = s + tb[o];
    }
    if (tid < 128) {
        float rstd = rsqrtf(v2[tid] + EPS);
        float s1 = g2[tid] * rstd;
        sc[tid] = s1;
        sh[tid] = b2[tid] - m2[tid] * s1;
    }
}

// ---------------- prep: shuffle weights, (tap,fout-half)-chunked 16x16x32 frags ----------------
// frag elem[lane*8+j] = W[ko][fin=ks*32+(lane>>4)*8+j][fout]
// W1s: chunk (ko*2+h) = 8KB of 8 frags w=ks*4+mtl; fout = h*64+mtl*16+(lane&15)
// W2s: chunk (ko*2+h) = 16KB of 16 frags w=ks*4+mtl (4 ks); same fout map
// rWs: 16 frags f: mt=f&7, ks=f>>3 (full fout; conv2 indexes its half)
__global__ __launch_bounds__(256) void k_shuffle(
        const float* __restrict__ W1, const float* __restrict__ W2,
        const float* __restrict__ rW,
        unsigned short* __restrict__ W1s, unsigned short* __restrict__ W2s,
        unsigned short* __restrict__ rWs) {
    int tid = blockIdx.x * 256 + threadIdx.x;
    const int n1 = 432 * 512, n2 = 864 * 512, n3 = 16 * 512;
    if (tid < n1) {
        int f = tid >> 9, r = tid & 511, lane = r >> 3, j = r & 7;
        int w = f & 7, mtl = w & 3, ks = w >> 2;
        int chunk = f >> 3, h = chunk & 1, ko = chunk >> 1;
        int fin = ks * 32 + (lane >> 4) * 8 + j;
        int fout = h * 64 + mtl * 16 + (lane & 15);
        W1s[tid] = f2bf(W1[(ko * 64 + fin) * 128 + fout]);
    } else if (tid < n1 + n2) {
        int e = tid - n1;
        int f = e >> 9, r = e & 511, lane = r >> 3, j = r & 7;
        int w = f & 15, mtl = w & 3, ks = w >> 2;
        int chunk = f >> 4, h = chunk & 1, ko = chunk >> 1;
        int fin = ks * 32 + (lane >> 4) * 8 + j;
        int fout = h * 64 + mtl * 16 + (lane & 15);
        W2s[e] = f2bf(W2[(ko * 128 + fin) * 128 + fout]);
    } else if (tid < n1 + n2 + n3) {
        int e = tid - n1 - n2;
        int f = e >> 9, r = e & 511, lane = r >> 3, j = r & 7;
        int mt = f & 7, ks = f >> 3;
        int fin = ks * 32 + (lane >> 4) * 8 + j;
        int fout = mt * 16 + (lane & 15);
        rWs[e] = f2bf(rW[fin * 128 + fout]);
    }
}

// ---------------- elementwise: h1 = bf16(silu(bn1(x))) ----------------
__global__ __launch_bounds__(256) void k_elem(
        const float* __restrict__ x,
        const float* __restrict__ g1, const float* __restrict__ b1,
        const float* __restrict__ m1, const float* __restrict__ v1,
        unsigned short* __restrict__ h1, int NV) {
    int tid = blockIdx.x * 256 + threadIdx.x;
    if (tid >= NV * 16) return;
    int n = tid >> 4, c = (tid & 15) << 2;
    f32x4 xv = *(const f32x4*)(x + n * 64 + c);
    f32x4 gv = *(const f32x4*)(g1 + c);
    f32x4 bv = *(const f32x4*)(b1 + c);
    f32x4 mv = *(const f32x4*)(m1 + c);
    f32x4 vv = *(const f32x4*)(v1 + c);
    u16x4 ho;
#pragma unroll
    for (int j = 0; j < 4; ++j) {
        float xn = (xv[j] - mv[j]) * rsqrtf(vv[j] + EPS) * gv[j] + bv[j];
        ho[j] = f2bf(silu_d(xn));
    }
    *(u16x4*)(h1 + n * 64 + c) = ho;
}

// ================= conv1: fout-split, 8-wave, 27-period dbuf =================
// block (vb,h): voxels [128vb,128vb+128) x fout [64h,64h+64)
__global__ __launch_bounds__(512) void k_conv1(
        const unsigned short* __restrict__ h1, const int* __restrict__ nbr,
        const unsigned char* __restrict__ mask, const unsigned short* __restrict__ W1s,
        const float* __restrict__ temb, const int* __restrict__ bidx,
        const float* __restrict__ bn2sc, const float* __restrict__ bn2sh,
        unsigned short* __restrict__ h2in, int NV) {
    __shared__ unsigned short lds0[4096];   // 8KB chunks
    __shared__ unsigned short lds1[4096];
    const int vb = blockIdx.x >> 1, h = blockIdx.x & 1;
    const int lane = threadIdx.x & 63;
    const int wave = threadIdx.x >> 6;      // 0..7
    const int g = lane >> 4, col = lane & 15;
    const int v = vb * 128 + wave * 16 + col;
    const bool vok = v < NV;
    const int msh = mask_shift(mask, NV);

    f32x4 acc[4];
    const f32x4 z4 = {0.f, 0.f, 0.f, 0.f};
#pragma unroll
    for (int m = 0; m < 4; ++m) acc[m] = z4;
    const s16x8 zz = {0, 0, 0, 0, 0, 0, 0, 0};

    auto loadr = [&](int t) -> int {
        if (!vok) return -1;
        int off = t * NV + v;
        int nv = nbr[off];
        bool mm = mask[(size_t)off << msh] != 0;
        return mm ? nv : -1;
    };

    // prologue: stage (0,h) -> buf0 (512 thr x 16B = 8KB); rows; B(tap0)
    {
        const char* src = (const char*)W1s + (size_t)h * 8192 + (size_t)threadIdx.x * 16;
        char* dst = (char*)lds0 + (size_t)threadIdx.x * 16;
        gload_lds16(src, dst);
    }
    int rA = loadr(0);
    int rN = loadr(1);
    int r0 = rA < 0 ? 0 : rA;
    s16x8 p0 = *(const s16x8*)(h1 + r0 * 64 + 0 * 32 + g * 8);
    s16x8 p1 = *(const s16x8*)(h1 + r0 * 64 + 1 * 32 + g * 8);
    __syncthreads();

    unsigned short* bufc = lds0;
    unsigned short* bufn = lds1;

    for (int t = 0; t < 27; ++t) {
        s16x8 q0, q1;
        int rN2 = -1;
        if (t < 26) {
            const char* src = (const char*)W1s + ((size_t)(t + 1) * 2 + h) * 8192 + (size_t)threadIdx.x * 16;
            char* dst = (char*)bufn + (size_t)threadIdx.x * 16;
            gload_lds16(src, dst);
            int rn = rN < 0 ? 0 : rN;
            q0 = *(const s16x8*)(h1 + rn * 64 + 0 * 32 + g * 8);
            q1 = *(const s16x8*)(h1 + rn * 64 + 1 * 32 + g * 8);
        }
        if (t < 25) rN2 = loadr(t + 2);
        const bool m = rA >= 0;
        s16x8 b0 = m ? p0 : zz;
        s16x8 b1 = m ? p1 : zz;
        const unsigned short* wp = bufc + lane * 8;
#pragma unroll
        for (int mtl = 0; mtl < 4; ++mtl) {
            s16x8 a = *(const s16x8*)(wp + (0 * 4 + mtl) * 512);
            acc[mtl] = __builtin_amdgcn_mfma_f32_16x16x32_bf16(a, b0, acc[mtl], 0, 0, 0);
        }
#pragma unroll
        for (int mtl = 0; mtl < 4; ++mtl) {
            s16x8 a = *(const s16x8*)(wp + (1 * 4 + mtl) * 512);
            acc[mtl] = __builtin_amdgcn_mfma_f32_16x16x32_bf16(a, b1, acc[mtl], 0, 0, 0);
        }
        if (t < 26) {
            __syncthreads();
            p0 = q0; p1 = q1;
            rA = rN; rN = rN2;
            unsigned short* tmp = bufc; bufc = bufn; bufn = tmp;
        }
    }

    if (vok) {
        int b = bidx[v];
        const float* te = temb + b * 128;
#pragma unroll
        for (int mtl = 0; mtl < 4; ++mtl) {
            int c = h * 64 + mtl * 16 + g * 4;
            f32x4 val = acc[mtl];
            f32x4 tv = *(const f32x4*)(te + c);
            f32x4 sc = *(const f32x4*)(bn2sc + c);
            f32x4 sh = *(const f32x4*)(bn2sh + c);
            u16x4 o;
#pragma unroll
            for (int j = 0; j < 4; ++j) {
                float zv = (val[j] + tv[j]) * sc[j] + sh[j];
                o[j] = f2bf(silu_d(zv));
            }
            *(u16x4*)(h2in + v * 128 + c) = o;
        }
    }
}

// ================= conv2: fout-split, 8-wave, 27-period dbuf + residual =================
__global__ __launch_bounds__(512) void k_conv2(
        const unsigned short* __restrict__ h2in, const int* __restrict__ nbr,
        const unsigned char* __restrict__ mask, const unsigned short* __restrict__ W2s,
        const float* __restrict__ x, const unsigned short* __restrict__ rWs,
        const float* __restrict__ resb, float* __restrict__ out, int NV) {
    __shared__ unsigned short lds0[8192];   // 16KB chunks
    __shared__ unsigned short lds1[8192];
    const int vb = blockIdx.x >> 1, h = blockIdx.x & 1;
    const int lane = threadIdx.x & 63;
    const int wave = threadIdx.x >> 6;      // 0..7
    const int g = lane >> 4, col = lane & 15;
    const int v = vb * 128 + wave * 16 + col;
    const bool vok = v < NV;
    const int msh = mask_shift(mask, NV);

    f32x4 acc[4];
    const f32x4 z4 = {0.f, 0.f, 0.f, 0.f};
#pragma unroll
    for (int m = 0; m < 4; ++m) acc[m] = z4;
    const s16x8 zz = {0, 0, 0, 0, 0, 0, 0, 0};

    auto loadr = [&](int t) -> int {
        if (!vok) return -1;
        int off = t * NV + v;
        int nv = nbr[off];
        bool mm = mask[(size_t)off << msh] != 0;
        return mm ? nv : -1;
    };

    // prologue: stage (0,h)->buf0 (512 thr x 2 x 16B = 16KB); rows; B(tap0); residual
    {
        const char* src = (const char*)W2s + (size_t)h * 16384 + (size_t)threadIdx.x * 16;
        char* dst = (char*)lds0 + (size_t)threadIdx.x * 16;
#pragma unroll
        for (int i = 0; i < 2; ++i)
            gload_lds16(src + i * 8192, dst + i * 8192);
    }
    int rA = loadr(0);
    int rN = loadr(1);
    int r0 = rA < 0 ? 0 : rA;
    s16x8 p0 = *(const s16x8*)(h2in + r0 * 128 + 0 * 32 + g * 8);
    s16x8 p1 = *(const s16x8*)(h2in + r0 * 128 + 1 * 32 + g * 8);
    s16x8 p2 = *(const s16x8*)(h2in + r0 * 128 + 2 * 32 + g * 8);
    s16x8 p3 = *(const s16x8*)(h2in + r0 * 128 + 3 * 32 + g * 8);

    // residual GEMM for this fout half (rWs frag (ks*8 + h*4 + mtl))
    {
        int rv = vok ? v : 0;
#pragma unroll
        for (int ks = 0; ks < 2; ++ks) {
            f32x4 xa = *(const f32x4*)(x + rv * 64 + ks * 32 + g * 8);
            f32x4 xb = *(const f32x4*)(x + rv * 64 + ks * 32 + g * 8 + 4);
            s16x8 b;
#pragma unroll
            for (int j = 0; j < 4; ++j) {
                b[j]     = (short)f2bf(xa[j]);
                b[j + 4] = (short)f2bf(xb[j]);
            }
#pragma unroll
            for (int mtl = 0; mtl < 4; ++mtl) {
                s16x8 a = *(const s16x8*)(rWs + (ks * 8 + h * 4 + mtl) * 512 + lane * 8);
                acc[mtl] = __builtin_amdgcn_mfma_f32_16x16x32_bf16(a, b, acc[mtl], 0, 0, 0);
            }
        }
    }
    __syncthreads();

    unsigned short* bufc = lds0;
    unsigned short* bufn = lds1;

    for (int t = 0; t < 27; ++t) {
        s16x8 q0, q1, q2, q3;
        int rN2 = -1;
        if (t < 26) {
            const char* src = (const char*)W2s + ((size_t)(t + 1) * 2 + h) * 16384 + (size_t)threadIdx.x * 16;
            char* dst = (char*)bufn + (size_t)threadIdx.x * 16;
#pragma unroll
            for (int i = 0; i < 2; ++i)
                gload_lds16(src + i * 8192, dst + i * 8192);
            int rn = rN < 0 ? 0 : rN;
            q0 = *(const s16x8*)(h2in + rn * 128 + 0 * 32 + g * 8);
            q1 = *(const s16x8*)(h2in + rn * 128 + 1 * 32 + g * 8);
            q2 = *(const s16x8*)(h2in + rn * 128 + 2 * 32 + g * 8);
            q3 = *(const s16x8*)(h2in + rn * 128 + 3 * 32 + g * 8);
        }
        if (t < 25) rN2 = loadr(t + 2);
        const bool m = rA >= 0;
        s16x8 b0 = m ? p0 : zz;
        s16x8 b1 = m ? p1 : zz;
        s16x8 b2 = m ? p2 : zz;
        s16x8 b3 = m ? p3 : zz;
        const unsigned short* wp = bufc + lane * 8;
#pragma unroll
        for (int mtl = 0; mtl < 4; ++mtl) {
            s16x8 a = *(const s16x8*)(wp + (0 * 4 + mtl) * 512);
            acc[mtl] = __builtin_amdgcn_mfma_f32_16x16x32_bf16(a, b0, acc[mtl], 0, 0, 0);
        }
#pragma unroll
        for (int mtl = 0; mtl < 4; ++mtl) {
            s16x8 a = *(const s16x8*)(wp + (1 * 4 + mtl) * 512);
            acc[mtl] = __builtin_amdgcn_mfma_f32_16x16x32_bf16(a, b1, acc[mtl], 0, 0, 0);
        }
#pragma unroll
        for (int mtl = 0; mtl < 4; ++mtl) {
            s16x8 a = *(const s16x8*)(wp + (2 * 4 + mtl) * 512);
            acc[mtl] = __builtin_amdgcn_mfma_f32_16x16x32_bf16(a, b2, acc[mtl], 0, 0, 0);
        }
#pragma unroll
        for (int mtl = 0; mtl < 4; ++mtl) {
            s16x8 a = *(const s16x8*)(wp + (3 * 4 + mtl) * 512);
            acc[mtl] = __builtin_amdgcn_mfma_f32_16x16x32_bf16(a, b3, acc[mtl], 0, 0, 0);
        }
        if (t < 26) {
            __syncthreads();
            p0 = q0; p1 = q1; p2 = q2; p3 = q3;
            rA = rN; rN = rN2;
            unsigned short* tmp = bufc; bufc = bufn; bufn = tmp;
        }
    }

    if (vok) {
#pragma unroll
        for (int mtl = 0; mtl < 4; ++mtl) {
            int c = h * 64 + mtl * 16 + g * 4;
            f32x4 rr = acc[mtl] + *(const f32x4*)(resb + c);
            *(f32x4*)(out + v * 128 + c) = rr;
        }
    }
}

extern "C" void kernel_launch(void* const* d_in, const int* in_sizes, int n_in,
                              void* d_out, int out_size, void* d_ws, size_t ws_size,
                              hipStream_t stream) {
    const float* x          = (const float*)d_in[0];
    const int* bidx         = (const int*)d_in[1];
    const float* t          = (const float*)d_in[2];
    const int* nbr1         = (const int*)d_in[3];
    const unsigned char* mask1 = (const unsigned char*)d_in[4];
    const int* nbr2         = (const int*)d_in[5];
    const unsigned char* mask2 = (const unsigned char*)d_in[6];
    const float* bn1g       = (const float*)d_in[7];
    const float* bn1b       = (const float*)d_in[8];
    const float* bn1m       = (const float*)d_in[9];
    const float* bn1v       = (const float*)d_in[10];
    const float* W1         = (const float*)d_in[11];
    const float* tW         = (const float*)d_in[12];
    const float* tb         = (const float*)d_in[13];
    const float* bn2g       = (const float*)d_in[14];
    const float* bn2b       = (const float*)d_in[15];
    const float* bn2m       = (const float*)d_in[16];
    const float* bn2v       = (const float*)d_in[17];
    const float* W2         = (const float*)d_in[18];
    const float* rW         = (const float*)d_in[19];
    const float* resb       = (const float*)d_in[20];

    const int NV = in_sizes[0] / 64;
    const int B  = in_sizes[2] / 256;
    float* out = (float*)d_out;

    // workspace layout: small buffers first, total ~20.5 MB
    char* ws = (char*)d_ws;
    size_t o_W1s = 0;
    size_t o_W2s = o_W1s + (size_t)432 * 1024;
    size_t o_rWs = o_W2s + (size_t)864 * 1024;
    size_t o_te  = o_rWs + (size_t)16 * 1024;
    size_t o_sc  = o_te  + (size_t)B * 128 * 4;
    size_t o_sh  = o_sc  + 512;
    size_t o_h1  = o_sh  + 512;
    size_t o_h2  = o_h1  + (size_t)NV * 64 * 2;

    unsigned short* W1s  = (unsigned short*)(ws + o_W1s);
    unsigned short* W2s  = (unsigned short*)(ws + o_W2s);
    unsigned short* rWs  = (unsigned short*)(ws + o_rWs);
    float* temb  = (float*)(ws + o_te);
    float* bn2sc = (float*)(ws + o_sc);
    float* bn2sh = (float*)(ws + o_sh);
    unsigned short* h1   = (unsigned short*)(ws + o_h1);
    unsigned short* h2in = (unsigned short*)(ws + o_h2);

    k_prep_small<<<1, 512, 0, stream>>>(t, tW, tb, bn2g, bn2b, bn2m, bn2v,
                                        temb, bn2sc, bn2sh, B);
    {
        int total = (432 + 864 + 16) * 512;
        int grid = (total + 255) / 256;
        k_shuffle<<<grid, 256, 0, stream>>>(W1, W2, rW, W1s, W2s, rWs);
    }
    {
        int total = NV * 16;
        int grid = (total + 255) / 256;
        k_elem<<<grid, 256, 0, stream>>>(x, bn1g, bn1b, bn1m, bn1v, h1, NV);
    }
    {
        int NB = (NV + 127) / 128;
        k_conv1<<<NB * 2, 512, 0, stream>>>(h1, nbr1, mask1, W1s, temb, bidx,
                                            bn2sc, bn2sh, h2in, NV);
        k_conv2<<<NB * 2, 512, 0, stream>>>(h2in, nbr2, mask2, W2s, x, rWs,
                                            resb, out, NV);
    }
}

// Round 21
// 138.243 us; speedup vs baseline: 1.4416x; 1.4416x over previous
//
#include <hip/hip_runtime.h>

// SparseResidualBlock: bn1->silu->sparseconv1(+t_emb)->bn2->silu->sparseconv2 + (x@res_W+res_b)
// N=50000, FIN=64, FOUT=128, K=27, B=4, TEMB=256. Output f32 [N,128].
//
// R21 = R19 (champion, 143us: 8-wave blocks, rolled dbuf, depth-2 B-prefetch)
// with conv2 periods HALVED: full-tap 32KB chunks, 2x32KB LDS dbuf, 27
// periods x 32 MFMAs (was 54 x 16). R19 is grid-limited at 1.53 blk/CU, so
// 64KB LDS (cap 2 blk/CU) costs zero occupancy -- R10's objection obsolete.
// R20 lesson: chains x latency / concurrency; fewer chains at equal
// concurrency is the only clean win left. conv1 unchanged (27 periods).

#define EPS 1e-5f

typedef __attribute__((ext_vector_type(8))) short s16x8;
typedef __attribute__((ext_vector_type(4))) float f32x4;
typedef __attribute__((ext_vector_type(4))) unsigned short u16x4;

static __device__ __forceinline__ unsigned short f2bf(float f) {
    union { float f; unsigned u; } v; v.f = f;
    unsigned r = v.u + 0x7fffu + ((v.u >> 16) & 1u);   // RTNE
    return (unsigned short)(r >> 16);
}
static __device__ __forceinline__ float silu_d(float x) {
    return x / (1.f + __expf(-x));
}
static __device__ __forceinline__ void gload_lds16(const void* gsrc, void* ldst) {
    __builtin_amdgcn_global_load_lds(
        (const __attribute__((address_space(1))) unsigned int*)gsrc,
        (__attribute__((address_space(3))) unsigned int*)ldst, 16, 0, 0);
}
// mask stored as 1-byte bool (shift 0) or int32 (shift 2)? Probe a byte at a
// non-multiple-of-4 index inside the all-true center row (k=13).
static __device__ __forceinline__ int mask_shift(const unsigned char* mask, int NV) {
    size_t base = (size_t)13 * (size_t)NV;
    int v = ((base & 3) == 3) ? 2 : 1;
    return (mask[base + v] == 1) ? 0 : 2;
}

// ---------------- prep: t_emb + bn2 scale/shift ----------------
__global__ void k_prep_small(const float* __restrict__ t, const float* __restrict__ tW,
                             const float* __restrict__ tb,
                             const float* __restrict__ g2, const float* __restrict__ b2,
                             const float* __restrict__ m2, const float* __restrict__ v2,
                             float* __restrict__ temb, float* __restrict__ sc,
                             float* __restrict__ sh, int B) {
    int tid = threadIdx.x;
    if (tid < B * 128) {
        int b = tid >> 7, o = tid & 127;
        float s = 0.f;
        for (int e = 0; e < 256; ++e) {
            float tv = t[b * 256 + e];
            s += silu_d(tv) * tW[e * 128 + o];
        }
        temb[tid] = s + tb[o];
    }
    if (tid < 128) {
        float rstd = rsqrtf(v2[tid] + EPS);
        float s1 = g2[tid] * rstd;
        sc[tid] = s1;
        sh[tid] = b2[tid] - m2[tid] * s1;
    }
}

// ---------------- prep: shuffle weights to fragment-linear bf16 (16x16x32) ----------------
// frag elem[lane*8+j] = W[ko][fin=ks*32+(lane>>4)*8+j][fout=mt*16+(lane&15)]
// tap ko = contiguous frags [ko*F, ko*F+F): frag = ks*8 + mt (F=16 conv1, 32 conv2)
__global__ __launch_bounds__(256) void k_shuffle(
        const float* __restrict__ W1, const float* __restrict__ W2,
        const float* __restrict__ rW,
        unsigned short* __restrict__ W1s, unsigned short* __restrict__ W2s,
        unsigned short* __restrict__ rWs) {
    int tid = blockIdx.x * 256 + threadIdx.x;
    const int n1 = 432 * 512, n2 = 864 * 512, n3 = 16 * 512;
    if (tid < n1) {
        int f = tid >> 9, r = tid & 511, lane = r >> 3, j = r & 7;
        int mt = f & 7, fk = f >> 3, ks = fk & 1, ko = fk >> 1;
        int fin = ks * 32 + (lane >> 4) * 8 + j;
        int fout = mt * 16 + (lane & 15);
        W1s[tid] = f2bf(W1[(ko * 64 + fin) * 128 + fout]);
    } else if (tid < n1 + n2) {
        int e = tid - n1;
        int f = e >> 9, r = e & 511, lane = r >> 3, j = r & 7;
        int mt = f & 7, fk = f >> 3, ks = fk & 3, ko = fk >> 2;
        int fin = ks * 32 + (lane >> 4) * 8 + j;
        int fout = mt * 16 + (lane & 15);
        W2s[e] = f2bf(W2[(ko * 128 + fin) * 128 + fout]);
    } else if (tid < n1 + n2 + n3) {
        int e = tid - n1 - n2;
        int f = e >> 9, r = e & 511, lane = r >> 3, j = r & 7;
        int mt = f & 7, ks = f >> 3;
        int fin = ks * 32 + (lane >> 4) * 8 + j;
        int fout = mt * 16 + (lane & 15);
        rWs[e] = f2bf(rW[fin * 128 + fout]);
    }
}

// ---------------- elementwise: h1 = bf16(silu(bn1(x))) ----------------
__global__ __launch_bounds__(256) void k_elem(
        const float* __restrict__ x,
        const float* __restrict__ g1, const float* __restrict__ b1,
        const float* __restrict__ m1, const float* __restrict__ v1,
        unsigned short* __restrict__ h1, int NV) {
    int tid = blockIdx.x * 256 + threadIdx.x;
    if (tid >= NV * 16) return;
    int n = tid >> 4, c = (tid & 15) << 2;
    f32x4 xv = *(const f32x4*)(x + n * 64 + c);
    f32x4 gv = *(const f32x4*)(g1 + c);
    f32x4 bv = *(const f32x4*)(b1 + c);
    f32x4 mv = *(const f32x4*)(m1 + c);
    f32x4 vv = *(const f32x4*)(v1 + c);
    u16x4 ho;
#pragma unroll
    for (int j = 0; j < 4; ++j) {
        float xn = (xv[j] - mv[j]) * rsqrtf(vv[j] + EPS) * gv[j] + bv[j];
        ho[j] = f2bf(silu_d(xn));
    }
    *(u16x4*)(h1 + n * 64 + c) = ho;
}

// ================= conv1: 8-wave rolled 27-tap dbuf pipeline (= R19) =================
// h2in = bf16(silu(bn2(sparseconv(h1,W1) + temb[bidx])))
__global__ __launch_bounds__(512) void k_conv1(
        const unsigned short* __restrict__ h1, const int* __restrict__ nbr,
        const unsigned char* __restrict__ mask, const unsigned short* __restrict__ W1s,
        const float* __restrict__ temb, const int* __restrict__ bidx,
        const float* __restrict__ bn2sc, const float* __restrict__ bn2sh,
        unsigned short* __restrict__ h2in, int NV) {
    __shared__ unsigned short lds0[8192];
    __shared__ unsigned short lds1[8192];
    const int lane = threadIdx.x & 63;
    const int wave = threadIdx.x >> 6;          // 0..7
    const int g = lane >> 4, col = lane & 15;
    const int v = blockIdx.x * 128 + wave * 16 + col;
    const bool vok = v < NV;
    const int msh = mask_shift(mask, NV);

    f32x4 acc[8];
    const f32x4 z4 = {0.f, 0.f, 0.f, 0.f};
#pragma unroll
    for (int m = 0; m < 8; ++m) acc[m] = z4;
    const s16x8 zz = {0, 0, 0, 0, 0, 0, 0, 0};

    auto loadr = [&](int t) -> int {
        if (!vok) return -1;
        int off = t * NV + v;
        int nv = nbr[off];
        bool mm = mask[(size_t)off << msh] != 0;
        return mm ? nv : -1;
    };

    // prologue: stage tap0 -> buf0 (512 thr x 2 x 16B = 16KB); rows; B(tap0)
    {
        const char* src = (const char*)W1s + (size_t)threadIdx.x * 16;
        char* dst = (char*)lds0 + (size_t)threadIdx.x * 16;
#pragma unroll
        for (int i = 0; i < 2; ++i)
            gload_lds16(src + i * 8192, dst + i * 8192);
    }
    int rA = loadr(0);
    int rN = loadr(1);
    int r0 = rA < 0 ? 0 : rA;
    s16x8 p0 = *(const s16x8*)(h1 + r0 * 64 + 0 * 32 + g * 8);
    s16x8 p1 = *(const s16x8*)(h1 + r0 * 64 + 1 * 32 + g * 8);
    __syncthreads();

    unsigned short* bufc = lds0;
    unsigned short* bufn = lds1;

    for (int t = 0; t < 27; ++t) {
        s16x8 q0, q1;
        int rN2 = -1;
        if (t < 26) {
            const char* src = (const char*)W1s + (size_t)(t + 1) * 16384 + (size_t)threadIdx.x * 16;
            char* dst = (char*)bufn + (size_t)threadIdx.x * 16;
#pragma unroll
            for (int i = 0; i < 2; ++i)
                gload_lds16(src + i * 8192, dst + i * 8192);
            int rn = rN < 0 ? 0 : rN;
            q0 = *(const s16x8*)(h1 + rn * 64 + 0 * 32 + g * 8);
            q1 = *(const s16x8*)(h1 + rn * 64 + 1 * 32 + g * 8);
        }
        if (t < 25) rN2 = loadr(t + 2);
        const bool m = rA >= 0;
        s16x8 b0 = m ? p0 : zz;
        s16x8 b1 = m ? p1 : zz;
        const unsigned short* wp = bufc + lane * 8;
#pragma unroll
        for (int mt = 0; mt < 8; ++mt) {
            s16x8 a = *(const s16x8*)(wp + (0 * 8 + mt) * 512);
            acc[mt] = __builtin_amdgcn_mfma_f32_16x16x32_bf16(a, b0, acc[mt], 0, 0, 0);
        }
#pragma unroll
        for (int mt = 0; mt < 8; ++mt) {
            s16x8 a = *(const s16x8*)(wp + (1 * 8 + mt) * 512);
            acc[mt] = __builtin_amdgcn_mfma_f32_16x16x32_bf16(a, b1, acc[mt], 0, 0, 0);
        }
        if (t < 26) {
            __syncthreads();
            p0 = q0; p1 = q1;
            rA = rN; rN = rN2;
            unsigned short* tmp = bufc; bufc = bufn; bufn = tmp;
        }
    }

    if (vok) {
        int b = bidx[v];
        const float* te = temb + b * 128;
#pragma unroll
        for (int mt = 0; mt < 8; ++mt) {
            int c = mt * 16 + g * 4;
            f32x4 val = acc[mt];
            f32x4 tv = *(const f32x4*)(te + c);
            f32x4 sc = *(const f32x4*)(bn2sc + c);
            f32x4 sh = *(const f32x4*)(bn2sh + c);
            u16x4 o;
#pragma unroll
            for (int j = 0; j < 4; ++j) {
                float zv = (val[j] + tv[j]) * sc[j] + sh[j];
                o[j] = f2bf(silu_d(zv));
            }
            *(u16x4*)(h2in + v * 128 + c) = o;
        }
    }
}

// ================= conv2: 8-wave, FULL-TAP 32KB dbuf, 27 periods + residual =================
__global__ __launch_bounds__(512) void k_conv2(
        const unsigned short* __restrict__ h2in, const int* __restrict__ nbr,
        const unsigned char* __restrict__ mask, const unsigned short* __restrict__ W2s,
        const float* __restrict__ x, const unsigned short* __restrict__ rWs,
        const float* __restrict__ resb, float* __restrict__ out, int NV) {
    __shared__ unsigned short lds0[16384];  // 32KB = one full tap
    __shared__ unsigned short lds1[16384];
    const int lane = threadIdx.x & 63;
    const int wave = threadIdx.x >> 6;      // 0..7
    const int g = lane >> 4, col = lane & 15;
    const int v = blockIdx.x * 128 + wave * 16 + col;
    const bool vok = v < NV;
    const int msh = mask_shift(mask, NV);

    f32x4 acc[8];
    const f32x4 z4 = {0.f, 0.f, 0.f, 0.f};
#pragma unroll
    for (int m = 0; m < 8; ++m) acc[m] = z4;
    const s16x8 zz = {0, 0, 0, 0, 0, 0, 0, 0};

    auto loadr = [&](int t) -> int {
        if (!vok) return -1;
        int off = t * NV + v;
        int nv = nbr[off];
        bool mm = mask[(size_t)off << msh] != 0;
        return mm ? nv : -1;
    };

    // prologue: stage tap0 -> buf0 (512 thr x 4 x 16B = 32KB); rows; B(tap0); residual
    {
        const char* src = (const char*)W2s + (size_t)threadIdx.x * 16;
        char* dst = (char*)lds0 + (size_t)threadIdx.x * 16;
#pragma unroll
        for (int i = 0; i < 4; ++i)
            gload_lds16(src + i * 8192, dst + i * 8192);
    }
    int rA = loadr(0);
    int rN = loadr(1);
    int r0 = rA < 0 ? 0 : rA;
    s16x8 p0 = *(const s16x8*)(h2in + r0 * 128 + 0 * 32 + g * 8);
    s16x8 p1 = *(const s16x8*)(h2in + r0 * 128 + 1 * 32 + g * 8);
    s16x8 p2 = *(const s16x8*)(h2in + r0 * 128 + 2 * 32 + g * 8);
    s16x8 p3 = *(const s16x8*)(h2in + r0 * 128 + 3 * 32 + g * 8);

    // residual GEMM while tap0 stages (rWs tiny & L2-hot)
    {
        int rv = vok ? v : 0;
#pragma unroll
        for (int ks = 0; ks < 2; ++ks) {
            f32x4 xa = *(const f32x4*)(x + rv * 64 + ks * 32 + g * 8);
            f32x4 xb = *(const f32x4*)(x + rv * 64 + ks * 32 + g * 8 + 4);
            s16x8 b;
#pragma unroll
            for (int j = 0; j < 4; ++j) {
                b[j]     = (short)f2bf(xa[j]);
                b[j + 4] = (short)f2bf(xb[j]);
            }
            const unsigned short* wp = rWs + ks * 4096 + lane * 8;
#pragma unroll
            for (int mt = 0; mt < 8; ++mt) {
                s16x8 a = *(const s16x8*)(wp + mt * 512);
                acc[mt] = __builtin_amdgcn_mfma_f32_16x16x32_bf16(a, b, acc[mt], 0, 0, 0);
            }
        }
    }
    __syncthreads();   // tap0 staged; prologue gathers complete

    unsigned short* bufc = lds0;
    unsigned short* bufn = lds1;

    for (int t = 0; t < 27; ++t) {
        s16x8 q0, q1, q2, q3;
        int rN2 = -1;
        if (t < 26) {
            const char* src = (const char*)W2s + (size_t)(t + 1) * 32768 + (size_t)threadIdx.x * 16;
            char* dst = (char*)bufn + (size_t)threadIdx.x * 16;
#pragma unroll
            for (int i = 0; i < 4; ++i)
                gload_lds16(src + i * 8192, dst + i * 8192);
            int rn = rN < 0 ? 0 : rN;
            q0 = *(const s16x8*)(h2in + rn * 128 + 0 * 32 + g * 8);
            q1 = *(const s16x8*)(h2in + rn * 128 + 1 * 32 + g * 8);
            q2 = *(const s16x8*)(h2in + rn * 128 + 2 * 32 + g * 8);
            q3 = *(const s16x8*)(h2in + rn * 128 + 3 * 32 + g * 8);
        }
        if (t < 25) rN2 = loadr(t + 2);
        const bool m = rA >= 0;
        s16x8 b0 = m ? p0 : zz;
        s16x8 b1 = m ? p1 : zz;
        s16x8 b2 = m ? p2 : zz;
        s16x8 b3 = m ? p3 : zz;
        const unsigned short* wp = bufc + lane * 8;
#pragma unroll
        for (int mt = 0; mt < 8; ++mt) {
            s16x8 a = *(const s16x8*)(wp + (0 * 8 + mt) * 512);
            acc[mt] = __builtin_amdgcn_mfma_f32_16x16x32_bf16(a, b0, acc[mt], 0, 0, 0);
        }
#pragma unroll
        for (int mt = 0; mt < 8; ++mt) {
            s16x8 a = *(const s16x8*)(wp + (1 * 8 + mt) * 512);
            acc[mt] = __builtin_amdgcn_mfma_f32_16x16x32_bf16(a, b1, acc[mt], 0, 0, 0);
        }
#pragma unroll
        for (int mt = 0; mt < 8; ++mt) {
            s16x8 a = *(const s16x8*)(wp + (2 * 8 + mt) * 512);
            acc[mt] = __builtin_amdgcn_mfma_f32_16x16x32_bf16(a, b2, acc[mt], 0, 0, 0);
        }
#pragma unroll
        for (int mt = 0; mt < 8; ++mt) {
            s16x8 a = *(const s16x8*)(wp + (3 * 8 + mt) * 512);
            acc[mt] = __builtin_amdgcn_mfma_f32_16x16x32_bf16(a, b3, acc[mt], 0, 0, 0);
        }
        if (t < 26) {
            __syncthreads();
            p0 = q0; p1 = q1; p2 = q2; p3 = q3;
            rA = rN; rN = rN2;
            unsigned short* tmp = bufc; bufc = bufn; bufn = tmp;
        }
    }

    if (vok) {
#pragma unroll
        for (int mt = 0; mt < 8; ++mt) {
            int c = mt * 16 + g * 4;
            f32x4 rr = acc[mt] + *(const f32x4*)(resb + c);
            *(f32x4*)(out + v * 128 + c) = rr;
        }
    }
}

extern "C" void kernel_launch(void* const* d_in, const int* in_sizes, int n_in,
                              void* d_out, int out_size, void* d_ws, size_t ws_size,
                              hipStream_t stream) {
    const float* x          = (const float*)d_in[0];
    const int* bidx         = (const int*)d_in[1];
    const float* t          = (const float*)d_in[2];
    const int* nbr1         = (const int*)d_in[3];
    const unsigned char* mask1 = (const unsigned char*)d_in[4];
    const int* nbr2         = (const int*)d_in[5];
    const unsigned char* mask2 = (const unsigned char*)d_in[6];
    const float* bn1g       = (const float*)d_in[7];
    const float* bn1b       = (const float*)d_in[8];
    const float* bn1m       = (const float*)d_in[9];
    const float* bn1v       = (const float*)d_in[10];
    const float* W1         = (const float*)d_in[11];
    const float* tW         = (const float*)d_in[12];
    const float* tb         = (const float*)d_in[13];
    const float* bn2g       = (const float*)d_in[14];
    const float* bn2b       = (const float*)d_in[15];
    const float* bn2m       = (const float*)d_in[16];
    const float* bn2v       = (const float*)d_in[17];
    const float* W2         = (const float*)d_in[18];
    const float* rW         = (const float*)d_in[19];
    const float* resb       = (const float*)d_in[20];

    const int NV = in_sizes[0] / 64;
    const int B  = in_sizes[2] / 256;
    float* out = (float*)d_out;

    // workspace layout: small buffers first, total ~20.5 MB
    char* ws = (char*)d_ws;
    size_t o_W1s = 0;
    size_t o_W2s = o_W1s + (size_t)432 * 1024;
    size_t o_rWs = o_W2s + (size_t)864 * 1024;
    size_t o_te  = o_rWs + (size_t)16 * 1024;
    size_t o_sc  = o_te  + (size_t)B * 128 * 4;
    size_t o_sh  = o_sc  + 512;
    size_t o_h1  = o_sh  + 512;
    size_t o_h2  = o_h1  + (size_t)NV * 64 * 2;

    unsigned short* W1s  = (unsigned short*)(ws + o_W1s);
    unsigned short* W2s  = (unsigned short*)(ws + o_W2s);
    unsigned short* rWs  = (unsigned short*)(ws + o_rWs);
    float* temb  = (float*)(ws + o_te);
    float* bn2sc = (float*)(ws + o_sc);
    float* bn2sh = (float*)(ws + o_sh);
    unsigned short* h1   = (unsigned short*)(ws + o_h1);
    unsigned short* h2in = (unsigned short*)(ws + o_h2);

    k_prep_small<<<1, 512, 0, stream>>>(t, tW, tb, bn2g, bn2b, bn2m, bn2v,
                                        temb, bn2sc, bn2sh, B);
    {
        int total = (432 + 864 + 16) * 512;
        int grid = (total + 255) / 256;
        k_shuffle<<<grid, 256, 0, stream>>>(W1, W2, rW, W1s, W2s, rWs);
    }
    {
        int total = NV * 16;
        int grid = (total + 255) / 256;
        k_elem<<<grid, 256, 0, stream>>>(x, bn1g, bn1b, bn1m, bn1v, h1, NV);
    }
    {
        int grid = (NV + 127) / 128;
        k_conv1<<<grid, 512, 0, stream>>>(h1, nbr1, mask1, W1s, temb, bidx,
                                          bn2sc, bn2sh, h2in, NV);
        k_conv2<<<grid, 512, 0, stream>>>(h2in, nbr2, mask2, W2s, x, rWs,
                                          resb, out, NV);
    }
}

// Round 23
// 122.267 us; speedup vs baseline: 1.6299x; 1.1307x over previous
//
#include <hip/hip_runtime.h>

// SparseResidualBlock: bn1->silu->sparseconv1(+t_emb)->bn2->silu->sparseconv2 + (x@res_W+res_b)
// N=50000, FIN=64, FOUT=128, K=27, B=4, TEMB=256. Output f32 [N,128].
//
// R22 = R21 (8-wave full-tap dbuf; conv2 at 96% of LDS-port x imbalance
// bound) with two fixes:
//  1) grid BALANCE: 98-voxel / 7-wave (448-thr) blocks -> 511 blocks = 2/CU
//     exactly (was 391 -> 1.53/CU, 135 CUs serializing 2 rounds).
//     Port floor conv2 69->60us, conv1 35->30us.
//  2) prep+shuffle+elem FUSED into one kernel (was 3 serialized launches).
// Pipeline (rolled dbuf, depth-2 B-prefetch, 1 __syncthreads/period) intact.

#define EPS 1e-5f

typedef __attribute__((ext_vector_type(8))) short s16x8;
typedef __attribute__((ext_vector_type(4))) float f32x4;
typedef __attribute__((ext_vector_type(4))) unsigned short u16x4;

#define VPB 98            // voxels per conv block (7 waves x 16 slots = 112 cap)

static __device__ __forceinline__ unsigned short f2bf(float f) {
    union { float f; unsigned u; } v; v.f = f;
    unsigned r = v.u + 0x7fffu + ((v.u >> 16) & 1u);   // RTNE
    return (unsigned short)(r >> 16);
}
static __device__ __forceinline__ float silu_d(float x) {
    return x / (1.f + __expf(-x));
}
static __device__ __forceinline__ void gload_lds16(const void* gsrc, void* ldst) {
    __builtin_amdgcn_global_load_lds(
        (const __attribute__((address_space(1))) unsigned int*)gsrc,
        (__attribute__((address_space(3))) unsigned int*)ldst, 16, 0, 0);
}
// mask stored as 1-byte bool (shift 0) or int32 (shift 2)? Probe a byte at a
// non-multiple-of-4 index inside the all-true center row (k=13).
static __device__ __forceinline__ int mask_shift(const unsigned char* mask, int NV) {
    size_t base = (size_t)13 * (size_t)NV;
    int v = ((base & 3) == 3) ? 2 : 1;
    return (mask[base + v] == 1) ? 0 : 2;
}

// ========== fused prep: t_emb + bn2 scale/shift + weight shuffle + h1 ==========
// block 0,1: t_emb (512 dots); block 2: bn2 prep; blocks [3, 3+NSH): shuffle;
// blocks [3+NSH, 3+NSH+NEL): h1 elementwise.
#define NSH 2624    // (432+864+16)*512 / 256
__global__ __launch_bounds__(256) void k_prep_fused(
        const float* __restrict__ t, const float* __restrict__ tW,
        const float* __restrict__ tb,
        const float* __restrict__ g2, const float* __restrict__ b2,
        const float* __restrict__ m2, const float* __restrict__ v2,
        float* __restrict__ temb, float* __restrict__ sc, float* __restrict__ sh,
        const float* __restrict__ W1, const float* __restrict__ W2,
        const float* __restrict__ rW,
        unsigned short* __restrict__ W1s, unsigned short* __restrict__ W2s,
        unsigned short* __restrict__ rWs,
        const float* __restrict__ x,
        const float* __restrict__ g1, const float* __restrict__ b1,
        const float* __restrict__ m1, const float* __restrict__ v1,
        unsigned short* __restrict__ h1, int NV, int B) {
    const int bid = blockIdx.x;
    if (bid < 2) {
        int idx = bid * 256 + threadIdx.x;
        if (idx < B * 128) {
            int b = idx >> 7, o = idx & 127;
            float s = 0.f;
            for (int e = 0; e < 256; ++e) {
                float tv = t[b * 256 + e];
                s += silu_d(tv) * tW[e * 128 + o];
            }
            temb[idx] = s + tb[o];
        }
        return;
    }
    if (bid == 2) {
        int tid = threadIdx.x;
        if (tid < 128) {
            float rstd = rsqrtf(v2[tid] + EPS);
            float s1 = g2[tid] * rstd;
            sc[tid] = s1;
            sh[tid] = b2[tid] - m2[tid] * s1;
        }
        return;
    }
    if (bid < 3 + NSH) {
        int tid = (bid - 3) * 256 + threadIdx.x;
        const int n1 = 432 * 512, n2 = 864 * 512, n3 = 16 * 512;
        if (tid < n1) {
            int f = tid >> 9, r = tid & 511, lane = r >> 3, j = r & 7;
            int mt = f & 7, fk = f >> 3, ks = fk & 1, ko = fk >> 1;
            int fin = ks * 32 + (lane >> 4) * 8 + j;
            int fout = mt * 16 + (lane & 15);
            W1s[tid] = f2bf(W1[(ko * 64 + fin) * 128 + fout]);
        } else if (tid < n1 + n2) {
            int e = tid - n1;
            int f = e >> 9, r = e & 511, lane = r >> 3, j = r & 7;
            int mt = f & 7, fk = f >> 3, ks = fk & 3, ko = fk >> 2;
            int fin = ks * 32 + (lane >> 4) * 8 + j;
            int fout = mt * 16 + (lane & 15);
            W2s[e] = f2bf(W2[(ko * 128 + fin) * 128 + fout]);
        } else if (tid < n1 + n2 + n3) {
            int e = tid - n1 - n2;
            int f = e >> 9, r = e & 511, lane = r >> 3, j = r & 7;
            int mt = f & 7, ks = f >> 3;
            int fin = ks * 32 + (lane >> 4) * 8 + j;
            int fout = mt * 16 + (lane & 15);
            rWs[e] = f2bf(rW[fin * 128 + fout]);
        }
        return;
    }
    {
        int tid = (bid - 3 - NSH) * 256 + threadIdx.x;
        if (tid >= NV * 16) return;
        int n = tid >> 4, c = (tid & 15) << 2;
        f32x4 xv = *(const f32x4*)(x + n * 64 + c);
        f32x4 gv = *(const f32x4*)(g1 + c);
        f32x4 bv = *(const f32x4*)(b1 + c);
        f32x4 mv = *(const f32x4*)(m1 + c);
        f32x4 vv = *(const f32x4*)(v1 + c);
        u16x4 ho;
#pragma unroll
        for (int j = 0; j < 4; ++j) {
            float xn = (xv[j] - mv[j]) * rsqrtf(vv[j] + EPS) * gv[j] + bv[j];
            ho[j] = f2bf(silu_d(xn));
        }
        *(u16x4*)(h1 + n * 64 + c) = ho;
    }
}

// ================= conv1: 7-wave, 98 vox/block, rolled 27-tap dbuf =================
// h2in = bf16(silu(bn2(sparseconv(h1,W1) + temb[bidx])))
__global__ __launch_bounds__(448) void k_conv1(
        const unsigned short* __restrict__ h1, const int* __restrict__ nbr,
        const unsigned char* __restrict__ mask, const unsigned short* __restrict__ W1s,
        const float* __restrict__ temb, const int* __restrict__ bidx,
        const float* __restrict__ bn2sc, const float* __restrict__ bn2sh,
        unsigned short* __restrict__ h2in, int NV) {
    __shared__ unsigned short lds0[8192];
    __shared__ unsigned short lds1[8192];
    const int lane = threadIdx.x & 63;
    const int wave = threadIdx.x >> 6;          // 0..6
    const int g = lane >> 4, col = lane & 15;
    const int slot = wave * 16 + col;
    const int v = blockIdx.x * VPB + slot;
    const bool vok = (slot < VPB) && (v < NV);
    const int msh = mask_shift(mask, NV);

    f32x4 acc[8];
    const f32x4 z4 = {0.f, 0.f, 0.f, 0.f};
#pragma unroll
    for (int m = 0; m < 8; ++m) acc[m] = z4;
    const s16x8 zz = {0, 0, 0, 0, 0, 0, 0, 0};

    auto loadr = [&](int t) -> int {
        if (!vok) return -1;
        int off = t * NV + v;
        int nv = nbr[off];
        bool mm = mask[(size_t)off << msh] != 0;
        return mm ? nv : -1;
    };

    // prologue: stage tap0 -> buf0 (448 thr, 16B stride 7168); rows; B(tap0)
    for (int off = threadIdx.x * 16; off < 16384; off += 7168)
        gload_lds16((const char*)W1s + off, (char*)lds0 + off);
    int rA = loadr(0);
    int rN = loadr(1);
    int r0 = rA < 0 ? 0 : rA;
    s16x8 p0 = *(const s16x8*)(h1 + r0 * 64 + 0 * 32 + g * 8);
    s16x8 p1 = *(const s16x8*)(h1 + r0 * 64 + 1 * 32 + g * 8);
    __syncthreads();

    unsigned short* bufc = lds0;
    unsigned short* bufn = lds1;

    for (int t = 0; t < 27; ++t) {
        s16x8 q0, q1;
        int rN2 = -1;
        if (t < 26) {
            const char* src = (const char*)W1s + (size_t)(t + 1) * 16384;
            for (int off = threadIdx.x * 16; off < 16384; off += 7168)
                gload_lds16(src + off, (char*)bufn + off);
            int rn = rN < 0 ? 0 : rN;
            q0 = *(const s16x8*)(h1 + rn * 64 + 0 * 32 + g * 8);
            q1 = *(const s16x8*)(h1 + rn * 64 + 1 * 32 + g * 8);
        }
        if (t < 25) rN2 = loadr(t + 2);
        const bool m = rA >= 0;
        s16x8 b0 = m ? p0 : zz;
        s16x8 b1 = m ? p1 : zz;
        const unsigned short* wp = bufc + lane * 8;
#pragma unroll
        for (int mt = 0; mt < 8; ++mt) {
            s16x8 a = *(const s16x8*)(wp + (0 * 8 + mt) * 512);
            acc[mt] = __builtin_amdgcn_mfma_f32_16x16x32_bf16(a, b0, acc[mt], 0, 0, 0);
        }
#pragma unroll
        for (int mt = 0; mt < 8; ++mt) {
            s16x8 a = *(const s16x8*)(wp + (1 * 8 + mt) * 512);
            acc[mt] = __builtin_amdgcn_mfma_f32_16x16x32_bf16(a, b1, acc[mt], 0, 0, 0);
        }
        if (t < 26) {
            __syncthreads();
            p0 = q0; p1 = q1;
            rA = rN; rN = rN2;
            unsigned short* tmp = bufc; bufc = bufn; bufn = tmp;
        }
    }

    if (vok) {
        int b = bidx[v];
        const float* te = temb + b * 128;
#pragma unroll
        for (int mt = 0; mt < 8; ++mt) {
            int c = mt * 16 + g * 4;
            f32x4 val = acc[mt];
            f32x4 tv = *(const f32x4*)(te + c);
            f32x4 sc = *(const f32x4*)(bn2sc + c);
            f32x4 sh = *(const f32x4*)(bn2sh + c);
            u16x4 o;
#pragma unroll
            for (int j = 0; j < 4; ++j) {
                float zv = (val[j] + tv[j]) * sc[j] + sh[j];
                o[j] = f2bf(silu_d(zv));
            }
            *(u16x4*)(h2in + v * 128 + c) = o;
        }
    }
}

// ========= conv2: 7-wave, 98 vox/block, FULL-TAP 32KB dbuf, 27 periods + residual =========
__global__ __launch_bounds__(448) void k_conv2(
        const unsigned short* __restrict__ h2in, const int* __restrict__ nbr,
        const unsigned char* __restrict__ mask, const unsigned short* __restrict__ W2s,
        const float* __restrict__ x, const unsigned short* __restrict__ rWs,
        const float* __restrict__ resb, float* __restrict__ out, int NV) {
    __shared__ unsigned short lds0[16384];  // 32KB = one full tap
    __shared__ unsigned short lds1[16384];
    const int lane = threadIdx.x & 63;
    const int wave = threadIdx.x >> 6;      // 0..6
    const int g = lane >> 4, col = lane & 15;
    const int slot = wave * 16 + col;
    const int v = blockIdx.x * VPB + slot;
    const bool vok = (slot < VPB) && (v < NV);
    const int msh = mask_shift(mask, NV);

    f32x4 acc[8];
    const f32x4 z4 = {0.f, 0.f, 0.f, 0.f};
#pragma unroll
    for (int m = 0; m < 8; ++m) acc[m] = z4;
    const s16x8 zz = {0, 0, 0, 0, 0, 0, 0, 0};

    auto loadr = [&](int t) -> int {
        if (!vok) return -1;
        int off = t * NV + v;
        int nv = nbr[off];
        bool mm = mask[(size_t)off << msh] != 0;
        return mm ? nv : -1;
    };

    // prologue: stage tap0 -> buf0; rows; B(tap0); residual GEMM
    for (int off = threadIdx.x * 16; off < 32768; off += 7168)
        gload_lds16((const char*)W2s + off, (char*)lds0 + off);
    int rA = loadr(0);
    int rN = loadr(1);
    int r0 = rA < 0 ? 0 : rA;
    s16x8 p0 = *(const s16x8*)(h2in + r0 * 128 + 0 * 32 + g * 8);
    s16x8 p1 = *(const s16x8*)(h2in + r0 * 128 + 1 * 32 + g * 8);
    s16x8 p2 = *(const s16x8*)(h2in + r0 * 128 + 2 * 32 + g * 8);
    s16x8 p3 = *(const s16x8*)(h2in + r0 * 128 + 3 * 32 + g * 8);

    // residual GEMM while tap0 stages (rWs tiny & L2-hot)
    {
        int rv = vok ? v : 0;
#pragma unroll
        for (int ks = 0; ks < 2; ++ks) {
            f32x4 xa = *(const f32x4*)(x + rv * 64 + ks * 32 + g * 8);
            f32x4 xb = *(const f32x4*)(x + rv * 64 + ks * 32 + g * 8 + 4);
            s16x8 b;
#pragma unroll
            for (int j = 0; j < 4; ++j) {
                b[j]     = (short)f2bf(xa[j]);
                b[j + 4] = (short)f2bf(xb[j]);
            }
            const unsigned short* wp = rWs + ks * 4096 + lane * 8;
#pragma unroll
            for (int mt = 0; mt < 8; ++mt) {
                s16x8 a = *(const s16x8*)(wp + mt * 512);
                acc[mt] = __builtin_amdgcn_mfma_f32_16x16x32_bf16(a, b, acc[mt], 0, 0, 0);
            }
        }
    }
    __syncthreads();   // tap0 staged; prologue gathers complete

    unsigned short* bufc = lds0;
    unsigned short* bufn = lds1;

    for (int t = 0; t < 27; ++t) {
        s16x8 q0, q1, q2, q3;
        int rN2 = -1;
        if (t < 26) {
            const char* src = (const char*)W2s + (size_t)(t + 1) * 32768;
            for (int off = threadIdx.x * 16; off < 32768; off += 7168)
                gload_lds16(src + off, (char*)bufn + off);
            int rn = rN < 0 ? 0 : rN;
            q0 = *(const s16x8*)(h2in + rn * 128 + 0 * 32 + g * 8);
            q1 = *(const s16x8*)(h2in + rn * 128 + 1 * 32 + g * 8);
            q2 = *(const s16x8*)(h2in + rn * 128 + 2 * 32 + g * 8);
            q3 = *(const s16x8*)(h2in + rn * 128 + 3 * 32 + g * 8);
        }
        if (t < 25) rN2 = loadr(t + 2);
        const bool m = rA >= 0;
        s16x8 b0 = m ? p0 : zz;
        s16x8 b1 = m ? p1 : zz;
        s16x8 b2 = m ? p2 : zz;
        s16x8 b3 = m ? p3 : zz;
        const unsigned short* wp = bufc + lane * 8;
#pragma unroll
        for (int mt = 0; mt < 8; ++mt) {
            s16x8 a = *(const s16x8*)(wp + (0 * 8 + mt) * 512);
            acc[mt] = __builtin_amdgcn_mfma_f32_16x16x32_bf16(a, b0, acc[mt], 0, 0, 0);
        }
#pragma unroll
        for (int mt = 0; mt < 8; ++mt) {
            s16x8 a = *(const s16x8*)(wp + (1 * 8 + mt) * 512);
            acc[mt] = __builtin_amdgcn_mfma_f32_16x16x32_bf16(a, b1, acc[mt], 0, 0, 0);
        }
#pragma unroll
        for (int mt = 0; mt < 8; ++mt) {
            s16x8 a = *(const s16x8*)(wp + (2 * 8 + mt) * 512);
            acc[mt] = __builtin_amdgcn_mfma_f32_16x16x32_bf16(a, b2, acc[mt], 0, 0, 0);
        }
#pragma unroll
        for (int mt = 0; mt < 8; ++mt) {
            s16x8 a = *(const s16x8*)(wp + (3 * 8 + mt) * 512);
            acc[mt] = __builtin_amdgcn_mfma_f32_16x16x32_bf16(a, b3, acc[mt], 0, 0, 0);
        }
        if (t < 26) {
            __syncthreads();
            p0 = q0; p1 = q1; p2 = q2; p3 = q3;
            rA = rN; rN = rN2;
            unsigned short* tmp = bufc; bufc = bufn; bufn = tmp;
        }
    }

    if (vok) {
#pragma unroll
        for (int mt = 0; mt < 8; ++mt) {
            int c = mt * 16 + g * 4;
            f32x4 rr = acc[mt] + *(const f32x4*)(resb + c);
            *(f32x4*)(out + v * 128 + c) = rr;
        }
    }
}

extern "C" void kernel_launch(void* const* d_in, const int* in_sizes, int n_in,
                              void* d_out, int out_size, void* d_ws, size_t ws_size,
                              hipStream_t stream) {
    const float* x          = (const float*)d_in[0];
    const int* bidx         = (const int*)d_in[1];
    const float* t          = (const float*)d_in[2];
    const int* nbr1         = (const int*)d_in[3];
    const unsigned char* mask1 = (const unsigned char*)d_in[4];
    const int* nbr2         = (const int*)d_in[5];
    const unsigned char* mask2 = (const unsigned char*)d_in[6];
    const float* bn1g       = (const float*)d_in[7];
    const float* bn1b       = (const float*)d_in[8];
    const float* bn1m       = (const float*)d_in[9];
    const float* bn1v       = (const float*)d_in[10];
    const float* W1         = (const float*)d_in[11];
    const float* tW         = (const float*)d_in[12];
    const float* tb         = (const float*)d_in[13];
    const float* bn2g       = (const float*)d_in[14];
    const float* bn2b       = (const float*)d_in[15];
    const float* bn2m       = (const float*)d_in[16];
    const float* bn2v       = (const float*)d_in[17];
    const float* W2         = (const float*)d_in[18];
    const float* rW         = (const float*)d_in[19];
    const float* resb       = (const float*)d_in[20];

    const int NV = in_sizes[0] / 64;
    const int B  = in_sizes[2] / 256;
    float* out = (float*)d_out;

    // workspace layout: small buffers first, total ~20.5 MB
    char* ws = (char*)d_ws;
    size_t o_W1s = 0;
    size_t o_W2s = o_W1s + (size_t)432 * 1024;
    size_t o_rWs = o_W2s + (size_t)864 * 1024;
    size_t o_te  = o_rWs + (size_t)16 * 1024;
    size_t o_sc  = o_te  + (size_t)B * 128 * 4;
    size_t o_sh  = o_sc  + 512;
    size_t o_h1  = o_sh  + 512;
    size_t o_h2  = o_h1  + (size_t)NV * 64 * 2;

    unsigned short* W1s  = (unsigned short*)(ws + o_W1s);
    unsigned short* W2s  = (unsigned short*)(ws + o_W2s);
    unsigned short* rWs  = (unsigned short*)(ws + o_rWs);
    float* temb  = (float*)(ws + o_te);
    float* bn2sc = (float*)(ws + o_sc);
    float* bn2sh = (float*)(ws + o_sh);
    unsigned short* h1   = (unsigned short*)(ws + o_h1);
    unsigned short* h2in = (unsigned short*)(ws + o_h2);

    {
        int nel = (NV * 16 + 255) / 256;
        int grid = 3 + NSH + nel;
        k_prep_fused<<<grid, 256, 0, stream>>>(
            t, tW, tb, bn2g, bn2b, bn2m, bn2v, temb, bn2sc, bn2sh,
            W1, W2, rW, W1s, W2s, rWs,
            x, bn1g, bn1b, bn1m, bn1v, h1, NV, B);
    }
    {
        int grid = (NV + VPB - 1) / VPB;
        k_conv1<<<grid, 448, 0, stream>>>(h1, nbr1, mask1, W1s, temb, bidx,
                                          bn2sc, bn2sh, h2in, NV);
        k_conv2<<<grid, 448, 0, stream>>>(h2in, nbr2, mask2, W2s, x, rWs,
                                          resb, out, NV);
    }
}